// Round 1
// 391.987 us; speedup vs baseline: 1.0084x; 1.0084x over previous
//
#include <hip/hip_runtime.h>

// GTN_MultiHeadAttention: B=8,S=1024,D=512,H=8,hd=64, N=H*B=64.
// Round 5: global_load_lds(16B) staging everywhere (m97 technique) with
// both-sides XOR swizzle (slot ^= row&7; pre-swizzled global source, swizzled
// ds_read — rule #21). k_attn: K staged linearly into front of K/P union,
// P keeps 136-stride; removed the P-visibility barrier (P write->read is
// wave-local, lgkmcnt orders it); heavy/light block pairing so each CU's two
// co-resident blocks sum to ~constant work.

typedef unsigned short u16;
typedef unsigned int u32;
typedef __attribute__((ext_vector_type(8))) short bf8;   // 8 bf16 (16B)
typedef __attribute__((ext_vector_type(4))) float f4;

__device__ __forceinline__ u16 f2bf(float f) {
    u32 x = __builtin_bit_cast(u32, f);
    return (u16)((x + 0x7FFFu + ((x >> 16) & 1u)) >> 16);  // RNE
}

#define MFMA16(a, b, c) __builtin_amdgcn_mfma_f32_16x16x32_bf16((a), (b), (c), 0, 0, 0)

// async global->LDS, 16B per lane; LDS dest = wave-uniform base + lane*16
#define GLD16(gp, lp) __builtin_amdgcn_global_load_lds( \
    (const __attribute__((address_space(1))) unsigned int*)(gp), \
    (__attribute__((address_space(3))) unsigned int*)(lp), 16, 0, 0)

// ---------------- cvt: x fp32 -> bf16 ----------------
__global__ __launch_bounds__(256) void k_cvt_x(const float4* __restrict__ xi,
                                               ushort4* __restrict__ xo)
{
    int idx = blockIdx.x * 256 + threadIdx.x;
    for (int i = idx; i < 1048576; i += 262144) {
        float4 f = xi[i];
        ushort4 o;
        o.x = f2bf(f.x); o.y = f2bf(f.y); o.z = f2bf(f.z); o.w = f2bf(f.w);
        xo[i] = o;
    }
}

// ---------------- cvt: W fp32 [k][c] -> bf16 transposed [c][k] ----------------
__global__ __launch_bounds__(256) void k_cvt_wT(
    const float* __restrict__ Wq, const float* __restrict__ Wk,
    const float* __restrict__ Wv, const float* __restrict__ Wo,
    u16* __restrict__ WqT, u16* __restrict__ WkT,
    u16* __restrict__ WvT, u16* __restrict__ WoT)
{
    const int z = blockIdx.z;
    const float* __restrict__ W = (z == 0) ? Wq : (z == 1) ? Wk : (z == 2) ? Wv : Wo;
    u16* __restrict__ WT        = (z == 0) ? WqT : (z == 1) ? WkT : (z == 2) ? WvT : WoT;

    __shared__ __align__(16) u16 Ts[64 * 72];
    const int k0 = blockIdx.x * 64, c0 = blockIdx.y * 64;
    const int tid = threadIdx.x;
    const int r = tid >> 4, cc = (tid & 15) * 4;
    #pragma unroll
    for (int rr = r; rr < 64; rr += 16) {
        float4 f = *(const float4*)&W[(size_t)(k0 + rr) * 512 + c0 + cc];
        Ts[(cc + 0) * 72 + rr] = f2bf(f.x);
        Ts[(cc + 1) * 72 + rr] = f2bf(f.y);
        Ts[(cc + 2) * 72 + rr] = f2bf(f.z);
        Ts[(cc + 3) * 72 + rr] = f2bf(f.w);
    }
    __syncthreads();
    #pragma unroll
    for (int i = 0; i < 2; ++i) {
        int gi = tid + i * 256;
        int cr = gi >> 3, g = gi & 7;
        bf8 v = *(bf8*)&Ts[cr * 72 + g * 8];
        *(bf8*)&WT[(size_t)(c0 + cr) * 512 + k0 + g * 8] = v;
    }
}

// ---------------- K1: QKV projection, MFMA ----------------
// grid (4 colTiles, 64 rowTiles, 3 weights), block 256 (4 waves, 2x2).
// Staging: global_load_lds 16B, linear [128][64] tiles, XOR-swizzled slots.
__global__ __launch_bounds__(256) void k_qkv(
    const u16* __restrict__ xb,
    const u16* __restrict__ WqT, const u16* __restrict__ WkT, const u16* __restrict__ WvT,
    const float* __restrict__ bq, const float* __restrict__ bk, const float* __restrict__ bv,
    u16* __restrict__ qb, u16* __restrict__ kb, u16* __restrict__ vT)
{
    const int which = blockIdx.z;
    const u16* __restrict__ WT     = (which == 0) ? WqT : (which == 1) ? WkT : WvT;
    const float* __restrict__ bias = (which == 0) ? bq : (which == 1) ? bk : bv;

    const int colTile = blockIdx.x * 128;
    const int rowTile = blockIdx.y * 128;

    __shared__ __align__(16) u16 As[128 * 64];
    __shared__ __align__(16) u16 Bs[128 * 64];

    const int tid = threadIdx.x;
    const int lane = tid & 63, w = tid >> 6;
    const int lm = lane & 15, kq = lane >> 4;
    const int mB = (w >> 1) * 64, nB = (w & 1) * 64;

    // staging geometry: lane covers row rb+sr, source slot sg = (lane&7)^sr
    const int sr = lane >> 3;
    const int sg = (lane & 7) ^ sr;

    f4 acc[4][4] = {};

    for (int k0 = 0; k0 < 512; k0 += 64) {
        __syncthreads();
        #pragma unroll
        for (int i = 0; i < 4; ++i) {
            const int rb = w * 32 + i * 8;
            GLD16(&xb[(size_t)(rowTile + rb + sr) * 512 + k0 + sg * 8], &As[rb * 64]);
            GLD16(&WT[(size_t)(colTile + rb + sr) * 512 + k0 + sg * 8], &Bs[rb * 64]);
        }
        __syncthreads();
        #pragma unroll
        for (int ks = 0; ks < 2; ++ks) {
            bf8 a[4], b[4];
            #pragma unroll
            for (int mi = 0; mi < 4; ++mi)
                a[mi] = *(bf8*)&As[(mB + mi * 16 + lm) * 64 + (((ks * 4 + kq) ^ (lm & 7)) * 8)];
            #pragma unroll
            for (int ni = 0; ni < 4; ++ni)
                b[ni] = *(bf8*)&Bs[(nB + ni * 16 + lm) * 64 + (((ks * 4 + kq) ^ (lm & 7)) * 8)];
            #pragma unroll
            for (int mi = 0; mi < 4; ++mi)
                #pragma unroll
                for (int ni = 0; ni < 4; ++ni)
                    acc[mi][ni] = MFMA16(a[mi], b[ni], acc[mi][ni]);
        }
    }

    if (which < 2) {
        u16* __restrict__ outp = (which == 0) ? qb : kb;
        #pragma unroll
        for (int mi = 0; mi < 4; ++mi) {
            const int r0 = rowTile + mB + mi * 16 + kq * 4;
            #pragma unroll
            for (int ni = 0; ni < 4; ++ni) {
                const int c = colTile + nB + ni * 16 + lm;
                const float bv_ = bias[c];
                const int h = c >> 6, hd = c & 63;
                #pragma unroll
                for (int rg = 0; rg < 4; ++rg) {
                    const int rr = r0 + rg;
                    const int b = rr >> 10, s = rr & 1023;
                    outp[(size_t)(((h * 8 + b) << 10) + s) * 64 + hd] = f2bf(acc[mi][ni][rg] + bv_);
                }
            }
        }
    } else {
        // v transposed: vT[(n*64+hd)*1024 + s]
        #pragma unroll
        for (int mi = 0; mi < 4; ++mi) {
            const int r0 = rowTile + mB + mi * 16 + kq * 4;  // 4-row group never crosses b
            const int b = r0 >> 10, s0 = r0 & 1023;
            #pragma unroll
            for (int ni = 0; ni < 4; ++ni) {
                const int c = colTile + nB + ni * 16 + lm;
                const float bv_ = bias[c];
                const int h = c >> 6, hd = c & 63;
                ushort4 pk;
                pk.x = f2bf(acc[mi][ni][0] + bv_);
                pk.y = f2bf(acc[mi][ni][1] + bv_);
                pk.z = f2bf(acc[mi][ni][2] + bv_);
                pk.w = f2bf(acc[mi][ni][3] + bv_);
                *(ushort4*)&vT[(size_t)((h * 8 + b) * 64 + hd) * 1024 + s0] = pk;
            }
        }
    }
}

// ---------------- K2: fused flash attention ----------------
// grid 512 (1D, heavy/light paired), block 256 = 4 waves, wave = 32 rows x 128 cols.
// K staged linearly (swizzled) into the front 16KB of KPs; P (softmax) reuses
// KPs with stride-136 rotation; V linear [64][128] swizzled.
__global__ __launch_bounds__(256) void k_attn(
    const u16* __restrict__ qb, const u16* __restrict__ kb, const u16* __restrict__ vT,
    float* __restrict__ heat, u16* __restrict__ wvb)
{
    const int bid = blockIdx.x;
    // pairing: bids 0..255 -> sT 7..4 (heavy), 256..511 -> sT 0..3 (light);
    // round-robin dispatch pairs (7,0),(6,1),(5,2),(4,3) per CU.
    const int sT = (bid < 256) ? (7 - (bid >> 6)) : ((bid >> 6) - 4);
    const int n = bid & 63;
    const int s0 = sT * 128;

    __shared__ __align__(16) u16 KPs[128 * 136];  // K linear [128][64] in first 16KB; P strided 136
    __shared__ __align__(16) u16 Vs[64 * 128];    // v^T tile [v][t], linear swizzled

    const int tid = threadIdx.x;
    const int lane = tid & 63, w = tid >> 6;
    const int lm = lane & 15, kq = lane >> 4;
    const int mB = w * 32;

    const int sr = lane >> 3, sg = (lane & 7) ^ sr;  // K staging
    const int vr = lane >> 4, vg = lane & 15;        // V staging

    const u16* __restrict__ qn = qb + (size_t)n * 65536;
    const u16* __restrict__ kn = kb + (size_t)n * 65536;
    const u16* __restrict__ vn = vT + (size_t)n * 65536;
    float* __restrict__ hp = heat + ((size_t)n << 20);

    // persistent q A-frags: rows s0+mB+mi*16+lm, k = ks*32+kq*8
    bf8 aq[2][2];
    #pragma unroll
    for (int mi = 0; mi < 2; ++mi)
        #pragma unroll
        for (int ks = 0; ks < 2; ++ks)
            aq[mi][ks] = *(const bf8*)&qn[(size_t)(s0 + mB + mi * 16 + lm) * 64 + ks * 32 + kq * 8];

    f4 accO[2][4] = {};
    float m_i[2][4], l_i[2][4];
    #pragma unroll
    for (int mi = 0; mi < 2; ++mi)
        #pragma unroll
        for (int rg = 0; rg < 4; ++rg) { m_i[mi][rg] = -3.0e38f; l_i[mi][rg] = 0.f; }

    for (int tt = 0; tt < 8; ++tt) {
        const int t0 = tt * 128;
        const bool causal = (tt <= sT);

        __syncthreads();  // prev-iter KPs(P)/Vs reads done before restage
        #pragma unroll
        for (int i = 0; i < 4; ++i) {
            const int rb = w * 32 + i * 8;
            GLD16(&kn[(size_t)(t0 + rb + sr) * 64 + sg * 8], &KPs[rb * 64]);
        }
        if (causal) {
            #pragma unroll
            for (int i = 0; i < 4; ++i) {
                const int rb = w * 16 + i * 4;
                const int r = rb + vr;
                GLD16(&vn[(size_t)r * 1024 + t0 + ((vg ^ (r & 7)) * 8)], &Vs[rb * 128]);
            }
        }
        __syncthreads();  // drains gld vmcnt; tiles visible

        // S = q @ k^T for this 128x128 tile (K read with XOR-swizzled slots)
        f4 accS[2][8] = {};
        #pragma unroll
        for (int ks = 0; ks < 2; ++ks) {
            bf8 b[8];
            #pragma unroll
            for (int ni = 0; ni < 8; ++ni)
                b[ni] = *(bf8*)&KPs[(ni * 16 + lm) * 64 + (((ks * 4 + kq) ^ (lm & 7)) * 8)];
            #pragma unroll
            for (int mi = 0; mi < 2; ++mi)
                #pragma unroll
                for (int ni = 0; ni < 8; ++ni)
                    accS[mi][ni] = MFMA16(aq[mi][ks], b[ni], accS[mi][ni]);
        }

        // raw heatmap write (unmasked, full matrix)
        #pragma unroll
        for (int mi = 0; mi < 2; ++mi) {
            #pragma unroll
            for (int rg = 0; rg < 4; ++rg) {
                float* rowp = &hp[(size_t)(s0 + mB + mi * 16 + kq * 4 + rg) * 1024 + t0 + lm];
                #pragma unroll
                for (int ni = 0; ni < 8; ++ni) rowp[ni * 16] = accS[mi][ni][rg];
            }
        }

        if (causal) {
            __syncthreads();  // all waves done reading K from KPs before P overwrite
            const bool diag = (tt == sT);
            #pragma unroll
            for (int mi = 0; mi < 2; ++mi) {
                #pragma unroll
                for (int rg = 0; rg < 4; ++rg) {
                    const int srow = s0 + mB + mi * 16 + kq * 4 + rg;
                    float tm = -3.0e38f;
                    #pragma unroll
                    for (int ni = 0; ni < 8; ++ni) {
                        float sv = accS[mi][ni][rg];
                        if (diag && (t0 + ni * 16 + lm > srow)) sv = -3.0e38f;
                        tm = fmaxf(tm, sv);
                    }
                    tm = fmaxf(tm, __shfl_xor(tm, 1));
                    tm = fmaxf(tm, __shfl_xor(tm, 2));
                    tm = fmaxf(tm, __shfl_xor(tm, 4));
                    tm = fmaxf(tm, __shfl_xor(tm, 8));
                    const float mn = fmaxf(m_i[mi][rg], tm);
                    const float alpha = __expf(m_i[mi][rg] - mn);
                    float rs = 0.f;
                    #pragma unroll
                    for (int ni = 0; ni < 8; ++ni) {
                        float sv = accS[mi][ni][rg];
                        const bool ok = !diag || (t0 + ni * 16 + lm <= srow);
                        float p = ok ? __expf(sv - mn) : 0.f;
                        rs += p;
                        KPs[(mB + mi * 16 + kq * 4 + rg) * 136 + ni * 16 + lm] = f2bf(p);
                    }
                    rs += __shfl_xor(rs, 1);
                    rs += __shfl_xor(rs, 2);
                    rs += __shfl_xor(rs, 4);
                    rs += __shfl_xor(rs, 8);
                    l_i[mi][rg] = l_i[mi][rg] * alpha + rs;
                    m_i[mi][rg] = mn;
                    #pragma unroll
                    for (int vni = 0; vni < 4; ++vni) accO[mi][vni][rg] *= alpha;
                }
            }
            // NO barrier here: P rows [mB, mB+32) are written and read by the
            // SAME wave; compiler-inserted lgkmcnt orders ds_write -> ds_read.

            // O += P @ V   (A = P from KPs[s][t] stride 136, B = V from Vs swizzled)
            #pragma unroll
            for (int ks = 0; ks < 4; ++ks) {
                bf8 a[2], b[4];
                #pragma unroll
                for (int mi = 0; mi < 2; ++mi)
                    a[mi] = *(bf8*)&KPs[(mB + mi * 16 + lm) * 136 + ks * 32 + kq * 8];
                #pragma unroll
                for (int vni = 0; vni < 4; ++vni)
                    b[vni] = *(bf8*)&Vs[(vni * 16 + lm) * 128 + (((ks * 4 + kq) ^ (lm & 7)) * 8)];
                #pragma unroll
                for (int mi = 0; mi < 2; ++mi)
                    #pragma unroll
                    for (int vni = 0; vni < 4; ++vni)
                        accO[mi][vni] = MFMA16(a[mi], b[vni], accO[mi][vni]);
            }
        }
    }

    // finalize: O /= l, write wv bf16 [n][s][64]
    u16* __restrict__ wn = wvb + (size_t)n * 65536;
    #pragma unroll
    for (int mi = 0; mi < 2; ++mi) {
        #pragma unroll
        for (int rg = 0; rg < 4; ++rg) {
            const float li = 1.0f / l_i[mi][rg];
            const int s = s0 + mB + mi * 16 + kq * 4 + rg;
            #pragma unroll
            for (int vni = 0; vni < 4; ++vni)
                wn[(size_t)s * 64 + vni * 16 + lm] = f2bf(accO[mi][vni][rg] * li);
        }
    }
}

// ---------------- K5: out = concat_heads(wv) @ Wo + bo ----------------
// grid (4 colTiles, 64 rowTiles), block 256; global_load_lds staging
__global__ __launch_bounds__(256) void k_out(
    const u16* __restrict__ wvb, const u16* __restrict__ WoT, const float* __restrict__ bo,
    float* __restrict__ outp)
{
    const int colTile = blockIdx.x * 128;
    const int rowTile = blockIdx.y * 128;
    const int b = rowTile >> 10, s0 = rowTile & 1023;

    __shared__ __align__(16) u16 As[128 * 64];
    __shared__ __align__(16) u16 Bs[128 * 64];

    const int tid = threadIdx.x;
    const int lane = tid & 63, w = tid >> 6;
    const int lm = lane & 15, kq = lane >> 4;
    const int mB = (w >> 1) * 64, nB = (w & 1) * 64;

    const int sr = lane >> 3;
    const int sg = (lane & 7) ^ sr;

    f4 acc[4][4] = {};

    for (int k0 = 0; k0 < 512; k0 += 64) {
        const int h = k0 >> 6;
        const u16* __restrict__ abase = wvb + (size_t)((h * 8 + b) * 1024 + s0) * 64;
        __syncthreads();
        #pragma unroll
        for (int i = 0; i < 4; ++i) {
            const int rb = w * 32 + i * 8;
            GLD16(&abase[(size_t)(rb + sr) * 64 + sg * 8], &As[rb * 64]);
            GLD16(&WoT[(size_t)(colTile + rb + sr) * 512 + k0 + sg * 8], &Bs[rb * 64]);
        }
        __syncthreads();
        #pragma unroll
        for (int ks = 0; ks < 2; ++ks) {
            bf8 a[4], b2[4];
            #pragma unroll
            for (int mi = 0; mi < 4; ++mi)
                a[mi] = *(bf8*)&As[(mB + mi * 16 + lm) * 64 + (((ks * 4 + kq) ^ (lm & 7)) * 8)];
            #pragma unroll
            for (int ni = 0; ni < 4; ++ni)
                b2[ni] = *(bf8*)&Bs[(nB + ni * 16 + lm) * 64 + (((ks * 4 + kq) ^ (lm & 7)) * 8)];
            #pragma unroll
            for (int mi = 0; mi < 4; ++mi)
                #pragma unroll
                for (int ni = 0; ni < 4; ++ni)
                    acc[mi][ni] = MFMA16(a[mi], b2[ni], acc[mi][ni]);
        }
    }

    #pragma unroll
    for (int mi = 0; mi < 4; ++mi) {
        const int r0 = rowTile + mB + mi * 16 + kq * 4;
        #pragma unroll
        for (int ni = 0; ni < 4; ++ni) {
            const int c = colTile + nB + ni * 16 + lm;
            const float bv_ = bo[c];
            #pragma unroll
            for (int rg = 0; rg < 4; ++rg)
                outp[(size_t)(r0 + rg) * 512 + c] = acc[mi][ni][rg] + bv_;
        }
    }
}

extern "C" void kernel_launch(void* const* d_in, const int* in_sizes, int n_in,
                              void* d_out, int out_size, void* d_ws, size_t ws_size,
                              hipStream_t stream)
{
    (void)in_sizes; (void)n_in; (void)out_size; (void)ws_size;

    const float* x  = (const float*)d_in[0];
    const float* Wq = (const float*)d_in[1];
    const float* bq = (const float*)d_in[2];
    const float* Wk = (const float*)d_in[3];
    const float* bk = (const float*)d_in[4];
    const float* Wv = (const float*)d_in[5];
    const float* bv = (const float*)d_in[6];
    const float* Wo = (const float*)d_in[7];
    const float* bo = (const float*)d_in[8];

    float* outp = (float*)d_out;             // [8,1024,512] fp32
    float* heat = outp + 4194304;            // [64,1024,1024] fp32

    u16* ws16 = (u16*)d_ws;
    u16* xb  = ws16;                          // [8192,512] bf16
    u16* WqT = xb  + 4194304;                 // [512,512] bf16 transposed
    u16* WkT = WqT + 262144;
    u16* WvT = WkT + 262144;
    u16* WoT = WvT + 262144;
    u16* qb  = WoT + 262144;                  // [64,1024,64] bf16
    u16* kb  = qb  + 4194304;                 // [64,1024,64] bf16
    u16* vT  = kb  + 4194304;                 // [64,64,1024] bf16 (v transposed)
    u16* wvb = vT  + 4194304;                 // [64,1024,64] bf16

    k_cvt_x <<<1024, 256, 0, stream>>>((const float4*)x, (ushort4*)xb);
    k_cvt_wT<<<dim3(8, 8, 4), 256, 0, stream>>>(Wq, Wk, Wv, Wo, WqT, WkT, WvT, WoT);
    k_qkv   <<<dim3(4, 64, 3), 256, 0, stream>>>(xb, WqT, WkT, WvT, bq, bk, bv, qb, kb, vT);
    k_attn  <<<dim3(512), 256, 0, stream>>>(qb, kb, vT, heat, wvb);
    k_out   <<<dim3(4, 64), 256, 0, stream>>>(wvb, WoT, bo, outp);
}

// Round 5
// 389.091 us; speedup vs baseline: 1.0159x; 1.0074x over previous
//
#include <hip/hip_runtime.h>

// GTN_MultiHeadAttention: B=8,S=1024,D=512,H=8,hd=64, N=H*B=64.
// Round 9 (= R7/R8 resubmit; two consecutive container-acquisition failures,
// construct set proven to execute on HW by R6): PV split into two 64-col
// half-passes overlaying Kb[cur] (exact 16KB), wave-local write->read ordered
// by lgkmcnt(0)+sched_barrier. K/V double-buffer prefetch, LDS-only mid-barrier
// (no vmcnt drain of heat stores/prefetch), non-temporal heat/out stores,
// setprio around MFMA clusters, heavy/light block pairing.

typedef unsigned short u16;
typedef unsigned int u32;
typedef __attribute__((ext_vector_type(8))) short bf8;   // 8 bf16 (16B)
typedef __attribute__((ext_vector_type(4))) float f4;

__device__ __forceinline__ u16 f2bf(float f) {
    u32 x = __builtin_bit_cast(u32, f);
    return (u16)((x + 0x7FFFu + ((x >> 16) & 1u)) >> 16);  // RNE
}

#define MFMA16(a, b, c) __builtin_amdgcn_mfma_f32_16x16x32_bf16((a), (b), (c), 0, 0, 0)

// async global->LDS, 16B per lane; LDS dest = wave-uniform base + lane*16
#define GLD16(gp, lp) __builtin_amdgcn_global_load_lds( \
    (const __attribute__((address_space(1))) unsigned int*)(gp), \
    (__attribute__((address_space(3))) unsigned int*)(lp), 16, 0, 0)

// ---------------- cvt: x fp32 -> bf16 ----------------
__global__ __launch_bounds__(256) void k_cvt_x(const float4* __restrict__ xi,
                                               ushort4* __restrict__ xo)
{
    int idx = blockIdx.x * 256 + threadIdx.x;
    for (int i = idx; i < 1048576; i += 262144) {
        float4 f = xi[i];
        ushort4 o;
        o.x = f2bf(f.x); o.y = f2bf(f.y); o.z = f2bf(f.z); o.w = f2bf(f.w);
        xo[i] = o;
    }
}

// ---------------- cvt: W fp32 [k][c] -> bf16 transposed [c][k] ----------------
__global__ __launch_bounds__(256) void k_cvt_wT(
    const float* __restrict__ Wq, const float* __restrict__ Wk,
    const float* __restrict__ Wv, const float* __restrict__ Wo,
    u16* __restrict__ WqT, u16* __restrict__ WkT,
    u16* __restrict__ WvT, u16* __restrict__ WoT)
{
    const int z = blockIdx.z;
    const float* __restrict__ W = (z == 0) ? Wq : (z == 1) ? Wk : (z == 2) ? Wv : Wo;
    u16* __restrict__ WT        = (z == 0) ? WqT : (z == 1) ? WkT : (z == 2) ? WvT : WoT;

    __shared__ __align__(16) u16 Ts[64 * 72];
    const int k0 = blockIdx.x * 64, c0 = blockIdx.y * 64;
    const int tid = threadIdx.x;
    const int r = tid >> 4, cc = (tid & 15) * 4;
    #pragma unroll
    for (int rr = r; rr < 64; rr += 16) {
        float4 f = *(const float4*)&W[(size_t)(k0 + rr) * 512 + c0 + cc];
        Ts[(cc + 0) * 72 + rr] = f2bf(f.x);
        Ts[(cc + 1) * 72 + rr] = f2bf(f.y);
        Ts[(cc + 2) * 72 + rr] = f2bf(f.z);
        Ts[(cc + 3) * 72 + rr] = f2bf(f.w);
    }
    __syncthreads();
    #pragma unroll
    for (int i = 0; i < 2; ++i) {
        int gi = tid + i * 256;
        int cr = gi >> 3, g = gi & 7;
        bf8 v = *(bf8*)&Ts[cr * 72 + g * 8];
        *(bf8*)&WT[(size_t)(c0 + cr) * 512 + k0 + g * 8] = v;
    }
}

// ---------------- K1: QKV projection, MFMA ----------------
// grid (4 colTiles, 64 rowTiles, 3 weights), block 256 (4 waves, 2x2).
// Staging: global_load_lds 16B, linear [128][64] tiles, XOR-swizzled slots.
__global__ __launch_bounds__(256) void k_qkv(
    const u16* __restrict__ xb,
    const u16* __restrict__ WqT, const u16* __restrict__ WkT, const u16* __restrict__ WvT,
    const float* __restrict__ bq, const float* __restrict__ bk, const float* __restrict__ bv,
    u16* __restrict__ qb, u16* __restrict__ kb, u16* __restrict__ vT)
{
    const int which = blockIdx.z;
    const u16* __restrict__ WT     = (which == 0) ? WqT : (which == 1) ? WkT : WvT;
    const float* __restrict__ bias = (which == 0) ? bq : (which == 1) ? bk : bv;

    const int colTile = blockIdx.x * 128;
    const int rowTile = blockIdx.y * 128;

    __shared__ __align__(16) u16 As[128 * 64];
    __shared__ __align__(16) u16 Bs[128 * 64];

    const int tid = threadIdx.x;
    const int lane = tid & 63, w = tid >> 6;
    const int lm = lane & 15, kq = lane >> 4;
    const int mB = (w >> 1) * 64, nB = (w & 1) * 64;

    const int sr = lane >> 3;
    const int sg = (lane & 7) ^ sr;

    f4 acc[4][4] = {};

    for (int k0 = 0; k0 < 512; k0 += 64) {
        __syncthreads();
        #pragma unroll
        for (int i = 0; i < 4; ++i) {
            const int rb = w * 32 + i * 8;
            GLD16(&xb[(size_t)(rowTile + rb + sr) * 512 + k0 + sg * 8], &As[rb * 64]);
            GLD16(&WT[(size_t)(colTile + rb + sr) * 512 + k0 + sg * 8], &Bs[rb * 64]);
        }
        __syncthreads();
        #pragma unroll
        for (int ks = 0; ks < 2; ++ks) {
            bf8 a[4], b[4];
            #pragma unroll
            for (int mi = 0; mi < 4; ++mi)
                a[mi] = *(bf8*)&As[(mB + mi * 16 + lm) * 64 + (((ks * 4 + kq) ^ (lm & 7)) * 8)];
            #pragma unroll
            for (int ni = 0; ni < 4; ++ni)
                b[ni] = *(bf8*)&Bs[(nB + ni * 16 + lm) * 64 + (((ks * 4 + kq) ^ (lm & 7)) * 8)];
            #pragma unroll
            for (int mi = 0; mi < 4; ++mi)
                #pragma unroll
                for (int ni = 0; ni < 4; ++ni)
                    acc[mi][ni] = MFMA16(a[mi], b[ni], acc[mi][ni]);
        }
    }

    if (which < 2) {
        u16* __restrict__ outp = (which == 0) ? qb : kb;
        #pragma unroll
        for (int mi = 0; mi < 4; ++mi) {
            const int r0 = rowTile + mB + mi * 16 + kq * 4;
            #pragma unroll
            for (int ni = 0; ni < 4; ++ni) {
                const int c = colTile + nB + ni * 16 + lm;
                const float bv_ = bias[c];
                const int h = c >> 6, hd = c & 63;
                #pragma unroll
                for (int rg = 0; rg < 4; ++rg) {
                    const int rr = r0 + rg;
                    const int b = rr >> 10, s = rr & 1023;
                    outp[(size_t)(((h * 8 + b) << 10) + s) * 64 + hd] = f2bf(acc[mi][ni][rg] + bv_);
                }
            }
        }
    } else {
        // v transposed: vT[(n*64+hd)*1024 + s]
        #pragma unroll
        for (int mi = 0; mi < 4; ++mi) {
            const int r0 = rowTile + mB + mi * 16 + kq * 4;  // 4-row group never crosses b
            const int b = r0 >> 10, s0 = r0 & 1023;
            #pragma unroll
            for (int ni = 0; ni < 4; ++ni) {
                const int c = colTile + nB + ni * 16 + lm;
                const float bv_ = bias[c];
                const int h = c >> 6, hd = c & 63;
                ushort4 pk;
                pk.x = f2bf(acc[mi][ni][0] + bv_);
                pk.y = f2bf(acc[mi][ni][1] + bv_);
                pk.z = f2bf(acc[mi][ni][2] + bv_);
                pk.w = f2bf(acc[mi][ni][3] + bv_);
                *(ushort4*)&vT[(size_t)((h * 8 + b) * 64 + hd) * 1024 + s0] = pk;
            }
        }
    }
}

// ---------------- K2: fused flash attention ----------------
// grid 512 (1D, heavy/light paired: bid and bid+256 co-resident on one CU),
// block 256 = 4 waves, wave = 32 rows x 128 cols.
// Double-buffered K[2]/V[2]; P overlays Kb[cur] in two 64-col half-passes.
__global__ __launch_bounds__(256) void k_attn(
    const u16* __restrict__ qb, const u16* __restrict__ kb, const u16* __restrict__ vT,
    float* __restrict__ heat, u16* __restrict__ wvb)
{
    const int bid = blockIdx.x;
    const int sT = (bid < 256) ? (7 - (bid >> 6)) : ((bid >> 6) - 4);
    const int n = bid & 63;
    const int s0 = sT * 128;

    __shared__ __align__(16) u16 Kb[2][128 * 64];  // K tile (tt); P half-tile (union)
    __shared__ __align__(16) u16 Vb[2][64 * 128];  // v^T tile [v][t]

    const int tid = threadIdx.x;
    const int lane = tid & 63, w = tid >> 6;
    const int lm = lane & 15, kq = lane >> 4;
    const int mB = w * 32;

    const int sr = lane >> 3, sg = (lane & 7) ^ sr;  // K staging
    const int vr = lane >> 4, vg = lane & 15;        // V staging

    const u16* __restrict__ qn = qb + (size_t)n * 65536;
    const u16* __restrict__ kn = kb + (size_t)n * 65536;
    const u16* __restrict__ vn = vT + (size_t)n * 65536;
    float* __restrict__ hp = heat + ((size_t)n << 20);

    // prologue: stage tile 0 into buffer 0 (tile 0 is always causal)
    #pragma unroll
    for (int i = 0; i < 4; ++i) {
        const int rb = w * 32 + i * 8;
        GLD16(&kn[(size_t)(rb + sr) * 64 + sg * 8], &Kb[0][rb * 64]);
    }
    #pragma unroll
    for (int i = 0; i < 4; ++i) {
        const int rb = w * 16 + i * 4;
        const int r = rb + vr;
        GLD16(&vn[(size_t)r * 1024 + ((vg ^ (r & 7)) * 8)], &Vb[0][rb * 128]);
    }

    // persistent q A-frags: rows s0+mB+mi*16+lm, k = ks*32+kq*8
    bf8 aq[2][2];
    #pragma unroll
    for (int mi = 0; mi < 2; ++mi)
        #pragma unroll
        for (int ks = 0; ks < 2; ++ks)
            aq[mi][ks] = *(const bf8*)&qn[(size_t)(s0 + mB + mi * 16 + lm) * 64 + ks * 32 + kq * 8];

    f4 accO[2][4] = {};
    float m_i[2][4], l_i[2][4];
    #pragma unroll
    for (int mi = 0; mi < 2; ++mi)
        #pragma unroll
        for (int rg = 0; rg < 4; ++rg) { m_i[mi][rg] = -3.0e38f; l_i[mi][rg] = 0.f; }

    int c = 0;
    for (int tt = 0; tt < 8; ++tt, c ^= 1) {
        const int t0 = tt * 128;
        const bool causal = (tt <= sT);
        u16* __restrict__ Kc = &Kb[c][0];
        u16* __restrict__ Vc = &Vb[c][0];

        __syncthreads();  // tile tt staged+visible; all prev-iter LDS reads done

        // prefetch tile tt+1 into the other buffer (hidden under this tile's work)
        if (tt < 7) {
            u16* __restrict__ Kn2 = &Kb[c ^ 1][0];
            #pragma unroll
            for (int i = 0; i < 4; ++i) {
                const int rb = w * 32 + i * 8;
                GLD16(&kn[(size_t)(t0 + 128 + rb + sr) * 64 + sg * 8], &Kn2[rb * 64]);
            }
            if (tt + 1 <= sT) {
                u16* __restrict__ Vn2 = &Vb[c ^ 1][0];
                #pragma unroll
                for (int i = 0; i < 4; ++i) {
                    const int rb = w * 16 + i * 4;
                    const int r = rb + vr;
                    GLD16(&vn[(size_t)r * 1024 + t0 + 128 + ((vg ^ (r & 7)) * 8)], &Vn2[rb * 128]);
                }
            }
        }

        // S = q @ k^T for this 128x128 tile (K read with XOR-swizzled slots)
        f4 accS[2][8] = {};
        __builtin_amdgcn_s_setprio(1);
        #pragma unroll
        for (int ks = 0; ks < 2; ++ks) {
            bf8 b[8];
            #pragma unroll
            for (int ni = 0; ni < 8; ++ni)
                b[ni] = *(bf8*)&Kc[(ni * 16 + lm) * 64 + (((ks * 4 + kq) ^ (lm & 7)) * 8)];
            #pragma unroll
            for (int mi = 0; mi < 2; ++mi)
                #pragma unroll
                for (int ni = 0; ni < 8; ++ni)
                    accS[mi][ni] = MFMA16(aq[mi][ks], b[ni], accS[mi][ni]);
        }
        __builtin_amdgcn_s_setprio(0);

        // raw heatmap write (unmasked, full matrix); non-temporal stream
        #pragma unroll
        for (int mi = 0; mi < 2; ++mi) {
            #pragma unroll
            for (int rg = 0; rg < 4; ++rg) {
                float* rowp = &hp[(size_t)(s0 + mB + mi * 16 + kq * 4 + rg) * 1024 + t0 + lm];
                #pragma unroll
                for (int ni = 0; ni < 8; ++ni)
                    __builtin_nontemporal_store(accS[mi][ni][rg], &rowp[ni * 16]);
            }
        }

        if (causal) {
            // LDS-only rendezvous: all waves' S-reads of Kc done before P
            // overwrite. No vmcnt drain (heat stores + prefetch stay in flight).
            asm volatile("s_waitcnt lgkmcnt(0)" ::: "memory");
            __builtin_amdgcn_s_barrier();
            __builtin_amdgcn_sched_barrier(0);

            const bool diag = (tt == sT);
            // softmax in registers: p values overwrite accS (heat already written)
            #pragma unroll
            for (int mi = 0; mi < 2; ++mi) {
                #pragma unroll
                for (int rg = 0; rg < 4; ++rg) {
                    const int srow = s0 + mB + mi * 16 + kq * 4 + rg;
                    float tm = -3.0e38f;
                    #pragma unroll
                    for (int ni = 0; ni < 8; ++ni) {
                        float sv = accS[mi][ni][rg];
                        if (diag && (t0 + ni * 16 + lm > srow)) sv = -3.0e38f;
                        tm = fmaxf(tm, sv);
                    }
                    tm = fmaxf(tm, __shfl_xor(tm, 1));
                    tm = fmaxf(tm, __shfl_xor(tm, 2));
                    tm = fmaxf(tm, __shfl_xor(tm, 4));
                    tm = fmaxf(tm, __shfl_xor(tm, 8));
                    const float mn = fmaxf(m_i[mi][rg], tm);
                    const float alpha = __expf(m_i[mi][rg] - mn);
                    float rs = 0.f;
                    #pragma unroll
                    for (int ni = 0; ni < 8; ++ni) {
                        float sv = accS[mi][ni][rg];
                        const bool ok = !diag || (t0 + ni * 16 + lm <= srow);
                        float p = ok ? __expf(sv - mn) : 0.f;
                        rs += p;
                        accS[mi][ni][rg] = p;
                    }
                    rs += __shfl_xor(rs, 1);
                    rs += __shfl_xor(rs, 2);
                    rs += __shfl_xor(rs, 4);
                    rs += __shfl_xor(rs, 8);
                    l_i[mi][rg] = l_i[mi][rg] * alpha + rs;
                    m_i[mi][rg] = mn;
                    #pragma unroll
                    for (int vni = 0; vni < 4; ++vni) accO[mi][vni][rg] *= alpha;
                }
            }

            // PV in two half-passes over t: P half (128 rows x 64 cols = 16KB)
            // overlays Kc. Write->read is wave-local (rows mB..mB+31); explicit
            // lgkmcnt(0) orders the DS clusters (per-wave in-order DS pipe).
            #pragma unroll
            for (int half = 0; half < 2; ++half) {
                #pragma unroll
                for (int mi = 0; mi < 2; ++mi) {
                    #pragma unroll
                    for (int rg = 0; rg < 4; ++rg) {
                        const int prow = mB + mi * 16 + kq * 4 + rg;
                        #pragma unroll
                        for (int nl = 0; nl < 4; ++nl) {
                            const float p = accS[mi][half * 4 + nl][rg];
                            Kc[prow * 64 + (((nl * 2 + (lm >> 3)) ^ (prow & 7)) * 8) + (lm & 7)] = f2bf(p);
                        }
                    }
                }
                asm volatile("s_waitcnt lgkmcnt(0)" ::: "memory");
                __builtin_amdgcn_sched_barrier(0);

                __builtin_amdgcn_s_setprio(1);
                #pragma unroll
                for (int kl = 0; kl < 2; ++kl) {
                    const int ks = half * 2 + kl;
                    bf8 a[2], b[4];
                    #pragma unroll
                    for (int mi = 0; mi < 2; ++mi)
                        a[mi] = *(bf8*)&Kc[(mB + mi * 16 + lm) * 64 + (((kl * 4 + kq) ^ (lm & 7)) * 8)];
                    #pragma unroll
                    for (int vni = 0; vni < 4; ++vni)
                        b[vni] = *(bf8*)&Vc[(vni * 16 + lm) * 128 + (((ks * 4 + kq) ^ (lm & 7)) * 8)];
                    #pragma unroll
                    for (int mi = 0; mi < 2; ++mi)
                        #pragma unroll
                        for (int vni = 0; vni < 4; ++vni)
                            accO[mi][vni] = MFMA16(a[mi], b[vni], accO[mi][vni]);
                }
                __builtin_amdgcn_s_setprio(0);

                if (half == 0) {
                    // half-0 a-frag reads must retire before half-1 overwrites
                    asm volatile("s_waitcnt lgkmcnt(0)" ::: "memory");
                    __builtin_amdgcn_sched_barrier(0);
                }
            }
        }
    }

    // finalize: O /= l, write wv bf16 [n][s][64]
    u16* __restrict__ wn = wvb + (size_t)n * 65536;
    #pragma unroll
    for (int mi = 0; mi < 2; ++mi) {
        #pragma unroll
        for (int rg = 0; rg < 4; ++rg) {
            const float li = 1.0f / l_i[mi][rg];
            const int s = s0 + mB + mi * 16 + kq * 4 + rg;
            #pragma unroll
            for (int vni = 0; vni < 4; ++vni)
                wn[(size_t)s * 64 + vni * 16 + lm] = f2bf(accO[mi][vni][rg] * li);
        }
    }
}

// ---------------- K5: out = concat_heads(wv) @ Wo + bo ----------------
// grid (4 colTiles, 64 rowTiles), block 256; global_load_lds staging
__global__ __launch_bounds__(256) void k_out(
    const u16* __restrict__ wvb, const u16* __restrict__ WoT, const float* __restrict__ bo,
    float* __restrict__ outp)
{
    const int colTile = blockIdx.x * 128;
    const int rowTile = blockIdx.y * 128;
    const int b = rowTile >> 10, s0 = rowTile & 1023;

    __shared__ __align__(16) u16 As[128 * 64];
    __shared__ __align__(16) u16 Bs[128 * 64];

    const int tid = threadIdx.x;
    const int lane = tid & 63, w = tid >> 6;
    const int lm = lane & 15, kq = lane >> 4;
    const int mB = (w >> 1) * 64, nB = (w & 1) * 64;

    const int sr = lane >> 3;
    const int sg = (lane & 7) ^ sr;

    f4 acc[4][4] = {};

    for (int k0 = 0; k0 < 512; k0 += 64) {
        const int h = k0 >> 6;
        const u16* __restrict__ abase = wvb + (size_t)((h * 8 + b) * 1024 + s0) * 64;
        __syncthreads();
        #pragma unroll
        for (int i = 0; i < 4; ++i) {
            const int rb = w * 32 + i * 8;
            GLD16(&abase[(size_t)(rb + sr) * 64 + sg * 8], &As[rb * 64]);
            GLD16(&WoT[(size_t)(colTile + rb + sr) * 512 + k0 + sg * 8], &Bs[rb * 64]);
        }
        __syncthreads();
        #pragma unroll
        for (int ks = 0; ks < 2; ++ks) {
            bf8 a[4], b2[4];
            #pragma unroll
            for (int mi = 0; mi < 4; ++mi)
                a[mi] = *(bf8*)&As[(mB + mi * 16 + lm) * 64 + (((ks * 4 + kq) ^ (lm & 7)) * 8)];
            #pragma unroll
            for (int ni = 0; ni < 4; ++ni)
                b2[ni] = *(bf8*)&Bs[(nB + ni * 16 + lm) * 64 + (((ks * 4 + kq) ^ (lm & 7)) * 8)];
            #pragma unroll
            for (int mi = 0; mi < 4; ++mi)
                #pragma unroll
                for (int ni = 0; ni < 4; ++ni)
                    acc[mi][ni] = MFMA16(a[mi], b2[ni], acc[mi][ni]);
        }
    }

    #pragma unroll
    for (int mi = 0; mi < 4; ++mi) {
        const int r0 = rowTile + mB + mi * 16 + kq * 4;
        #pragma unroll
        for (int ni = 0; ni < 4; ++ni) {
            const int c = colTile + nB + ni * 16 + lm;
            const float bv_ = bo[c];
            #pragma unroll
            for (int rg = 0; rg < 4; ++rg)
                __builtin_nontemporal_store(acc[mi][ni][rg] + bv_,
                                            &outp[(size_t)(r0 + rg) * 512 + c]);
        }
    }
}

extern "C" void kernel_launch(void* const* d_in, const int* in_sizes, int n_in,
                              void* d_out, int out_size, void* d_ws, size_t ws_size,
                              hipStream_t stream)
{
    (void)in_sizes; (void)n_in; (void)out_size; (void)ws_size;

    const float* x  = (const float*)d_in[0];
    const float* Wq = (const float*)d_in[1];
    const float* bq = (const float*)d_in[2];
    const float* Wk = (const float*)d_in[3];
    const float* bk = (const float*)d_in[4];
    const float* Wv = (const float*)d_in[5];
    const float* bv = (const float*)d_in[6];
    const float* Wo = (const float*)d_in[7];
    const float* bo = (const float*)d_in[8];

    float* outp = (float*)d_out;             // [8,1024,512] fp32
    float* heat = outp + 4194304;            // [64,1024,1024] fp32

    u16* ws16 = (u16*)d_ws;
    u16* xb  = ws16;                          // [8192,512] bf16
    u16* WqT = xb  + 4194304;                 // [512,512] bf16 transposed
    u16* WkT = WqT + 262144;
    u16* WvT = WkT + 262144;
    u16* WoT = WvT + 262144;
    u16* qb  = WoT + 262144;                  // [64,1024,64] bf16
    u16* kb  = qb  + 4194304;                 // [64,1024,64] bf16
    u16* vT  = kb  + 4194304;                 // [64,64,1024] bf16 (v transposed)
    u16* wvb = vT  + 4194304;                 // [64,1024,64] bf16

    k_cvt_x <<<1024, 256, 0, stream>>>((const float4*)x, (ushort4*)xb);
    k_cvt_wT<<<dim3(8, 8, 4), 256, 0, stream>>>(Wq, Wk, Wv, Wo, WqT, WkT, WvT, WoT);
    k_qkv   <<<dim3(4, 64, 3), 256, 0, stream>>>(xb, WqT, WkT, WvT, bq, bk, bv, qb, kb, vT);
    k_attn  <<<dim3(512), 256, 0, stream>>>(qb, kb, vT, heat, wvb);
    k_out   <<<dim3(4, 64), 256, 0, stream>>>(wvb, WoT, bo, outp);
}

// Round 6
// 379.984 us; speedup vs baseline: 1.0402x; 1.0240x over previous
//
#include <hip/hip_runtime.h>

// GTN_MultiHeadAttention: B=8,S=1024,D=512,H=8,hd=64, N=H*B=64.
// Round 10: k_attn occupancy attack. QBLK 128->64 (4 waves x 16 rows),
// grid 512->1024; LDS 64->48KB (K dbuf 2x16KB + single V 16KB) -> 3 blocks/CU
// = 12 waves/CU (was 8). XCD-aware mapping (bid%8 = n>>3: 8 heads' K/V = 2MB
// per XCD L2); work-balanced rT order {15,14,13,12,8,9,10,11,7,6,5,4,0,1,2,3}.
// Mid rendezvous = full vmcnt+lgkm drain + s_barrier (V visibility + P overlay;
// safe). P overlay half-pass scheme unchanged (HW-validated R5, absmax 0.25).
// k_qkv/k_out/cvt unchanged (verified).

typedef unsigned short u16;
typedef unsigned int u32;
typedef __attribute__((ext_vector_type(8))) short bf8;   // 8 bf16 (16B)
typedef __attribute__((ext_vector_type(4))) float f4;

__device__ __forceinline__ u16 f2bf(float f) {
    u32 x = __builtin_bit_cast(u32, f);
    return (u16)((x + 0x7FFFu + ((x >> 16) & 1u)) >> 16);  // RNE
}

#define MFMA16(a, b, c) __builtin_amdgcn_mfma_f32_16x16x32_bf16((a), (b), (c), 0, 0, 0)

// async global->LDS, 16B per lane; LDS dest = wave-uniform base + lane*16
#define GLD16(gp, lp) __builtin_amdgcn_global_load_lds( \
    (const __attribute__((address_space(1))) unsigned int*)(gp), \
    (__attribute__((address_space(3))) unsigned int*)(lp), 16, 0, 0)

// ---------------- cvt: x fp32 -> bf16 ----------------
__global__ __launch_bounds__(256) void k_cvt_x(const float4* __restrict__ xi,
                                               ushort4* __restrict__ xo)
{
    int idx = blockIdx.x * 256 + threadIdx.x;
    for (int i = idx; i < 1048576; i += 262144) {
        float4 f = xi[i];
        ushort4 o;
        o.x = f2bf(f.x); o.y = f2bf(f.y); o.z = f2bf(f.z); o.w = f2bf(f.w);
        xo[i] = o;
    }
}

// ---------------- cvt: W fp32 [k][c] -> bf16 transposed [c][k] ----------------
__global__ __launch_bounds__(256) void k_cvt_wT(
    const float* __restrict__ Wq, const float* __restrict__ Wk,
    const float* __restrict__ Wv, const float* __restrict__ Wo,
    u16* __restrict__ WqT, u16* __restrict__ WkT,
    u16* __restrict__ WvT, u16* __restrict__ WoT)
{
    const int z = blockIdx.z;
    const float* __restrict__ W = (z == 0) ? Wq : (z == 1) ? Wk : (z == 2) ? Wv : Wo;
    u16* __restrict__ WT        = (z == 0) ? WqT : (z == 1) ? WkT : (z == 2) ? WvT : WoT;

    __shared__ __align__(16) u16 Ts[64 * 72];
    const int k0 = blockIdx.x * 64, c0 = blockIdx.y * 64;
    const int tid = threadIdx.x;
    const int r = tid >> 4, cc = (tid & 15) * 4;
    #pragma unroll
    for (int rr = r; rr < 64; rr += 16) {
        float4 f = *(const float4*)&W[(size_t)(k0 + rr) * 512 + c0 + cc];
        Ts[(cc + 0) * 72 + rr] = f2bf(f.x);
        Ts[(cc + 1) * 72 + rr] = f2bf(f.y);
        Ts[(cc + 2) * 72 + rr] = f2bf(f.z);
        Ts[(cc + 3) * 72 + rr] = f2bf(f.w);
    }
    __syncthreads();
    #pragma unroll
    for (int i = 0; i < 2; ++i) {
        int gi = tid + i * 256;
        int cr = gi >> 3, g = gi & 7;
        bf8 v = *(bf8*)&Ts[cr * 72 + g * 8];
        *(bf8*)&WT[(size_t)(c0 + cr) * 512 + k0 + g * 8] = v;
    }
}

// ---------------- K1: QKV projection, MFMA ----------------
// grid (4 colTiles, 64 rowTiles, 3 weights), block 256 (4 waves, 2x2).
// Staging: global_load_lds 16B, linear [128][64] tiles, XOR-swizzled slots.
__global__ __launch_bounds__(256) void k_qkv(
    const u16* __restrict__ xb,
    const u16* __restrict__ WqT, const u16* __restrict__ WkT, const u16* __restrict__ WvT,
    const float* __restrict__ bq, const float* __restrict__ bk, const float* __restrict__ bv,
    u16* __restrict__ qb, u16* __restrict__ kb, u16* __restrict__ vT)
{
    const int which = blockIdx.z;
    const u16* __restrict__ WT     = (which == 0) ? WqT : (which == 1) ? WkT : WvT;
    const float* __restrict__ bias = (which == 0) ? bq : (which == 1) ? bk : bv;

    const int colTile = blockIdx.x * 128;
    const int rowTile = blockIdx.y * 128;

    __shared__ __align__(16) u16 As[128 * 64];
    __shared__ __align__(16) u16 Bs[128 * 64];

    const int tid = threadIdx.x;
    const int lane = tid & 63, w = tid >> 6;
    const int lm = lane & 15, kq = lane >> 4;
    const int mB = (w >> 1) * 64, nB = (w & 1) * 64;

    const int sr = lane >> 3;
    const int sg = (lane & 7) ^ sr;

    f4 acc[4][4] = {};

    for (int k0 = 0; k0 < 512; k0 += 64) {
        __syncthreads();
        #pragma unroll
        for (int i = 0; i < 4; ++i) {
            const int rb = w * 32 + i * 8;
            GLD16(&xb[(size_t)(rowTile + rb + sr) * 512 + k0 + sg * 8], &As[rb * 64]);
            GLD16(&WT[(size_t)(colTile + rb + sr) * 512 + k0 + sg * 8], &Bs[rb * 64]);
        }
        __syncthreads();
        #pragma unroll
        for (int ks = 0; ks < 2; ++ks) {
            bf8 a[4], b[4];
            #pragma unroll
            for (int mi = 0; mi < 4; ++mi)
                a[mi] = *(bf8*)&As[(mB + mi * 16 + lm) * 64 + (((ks * 4 + kq) ^ (lm & 7)) * 8)];
            #pragma unroll
            for (int ni = 0; ni < 4; ++ni)
                b[ni] = *(bf8*)&Bs[(nB + ni * 16 + lm) * 64 + (((ks * 4 + kq) ^ (lm & 7)) * 8)];
            #pragma unroll
            for (int mi = 0; mi < 4; ++mi)
                #pragma unroll
                for (int ni = 0; ni < 4; ++ni)
                    acc[mi][ni] = MFMA16(a[mi], b[ni], acc[mi][ni]);
        }
    }

    if (which < 2) {
        u16* __restrict__ outp = (which == 0) ? qb : kb;
        #pragma unroll
        for (int mi = 0; mi < 4; ++mi) {
            const int r0 = rowTile + mB + mi * 16 + kq * 4;
            #pragma unroll
            for (int ni = 0; ni < 4; ++ni) {
                const int c = colTile + nB + ni * 16 + lm;
                const float bv_ = bias[c];
                const int h = c >> 6, hd = c & 63;
                #pragma unroll
                for (int rg = 0; rg < 4; ++rg) {
                    const int rr = r0 + rg;
                    const int b = rr >> 10, s = rr & 1023;
                    outp[(size_t)(((h * 8 + b) << 10) + s) * 64 + hd] = f2bf(acc[mi][ni][rg] + bv_);
                }
            }
        }
    } else {
        // v transposed: vT[(n*64+hd)*1024 + s]
        #pragma unroll
        for (int mi = 0; mi < 4; ++mi) {
            const int r0 = rowTile + mB + mi * 16 + kq * 4;  // 4-row group never crosses b
            const int b = r0 >> 10, s0 = r0 & 1023;
            #pragma unroll
            for (int ni = 0; ni < 4; ++ni) {
                const int c = colTile + nB + ni * 16 + lm;
                const float bv_ = bias[c];
                const int h = c >> 6, hd = c & 63;
                ushort4 pk;
                pk.x = f2bf(acc[mi][ni][0] + bv_);
                pk.y = f2bf(acc[mi][ni][1] + bv_);
                pk.z = f2bf(acc[mi][ni][2] + bv_);
                pk.w = f2bf(acc[mi][ni][3] + bv_);
                *(ushort4*)&vT[(size_t)((h * 8 + b) * 64 + hd) * 1024 + s0] = pk;
            }
        }
    }
}

// ---------------- K2: fused flash attention ----------------
// grid 1024: bid -> xcd=bid&7, p=bid>>3, g=p&7, i=p>>3; n=xcd*8+g (K/V of 8
// heads stay in one XCD L2), rT=rt_order[i] (work-balanced), block = 4 waves
// x 16 q-rows = 64 rows. K double-buffered (prefetch tt+1), V single-buffered
// (issued at tile top, landed by mid drain). P overlays Kc in two 64-col
// half-passes (wave-local rows mB..mB+15).
__global__ __launch_bounds__(256, 3) void k_attn(
    const u16* __restrict__ qb, const u16* __restrict__ kb, const u16* __restrict__ vT,
    float* __restrict__ heat, u16* __restrict__ wvb)
{
    const int bid = blockIdx.x;
    const int p = bid >> 3;
    const int n = (bid & 7) * 8 + (p & 7);
    const int i4 = p >> 3;                 // 0..15
    const int q2 = i4 >> 2, j4 = i4 & 3;
    const int rT = (q2 == 0) ? 15 - j4 : (q2 == 1) ? 8 + j4 : (q2 == 2) ? 7 - j4 : j4;
    const int s0 = rT * 64;
    const int sTT = rT >> 1;               // last (diagonal) causal tile

    __shared__ __align__(16) u16 Kb[2][128 * 64];  // K tile; P half overlays [0:64) rows
    __shared__ __align__(16) u16 Vs[64 * 128];     // v^T tile [v][t], single buffer

    const int tid = threadIdx.x;
    const int lane = tid & 63, w = tid >> 6;
    const int lm = lane & 15, kq = lane >> 4;
    const int mB = w * 16;                 // wave's 16 q-rows

    const int sr = lane >> 3, sg = (lane & 7) ^ sr;  // K staging
    const int vr = lane >> 4, vg = lane & 15;        // V staging

    const u16* __restrict__ qn = qb + (size_t)n * 65536;
    const u16* __restrict__ kn = kb + (size_t)n * 65536;
    const u16* __restrict__ vn = vT + (size_t)n * 65536;
    float* __restrict__ hp = heat + ((size_t)n << 20);

    // prologue: stage K tile 0 into buffer 0
    #pragma unroll
    for (int ii = 0; ii < 4; ++ii) {
        const int rb = w * 32 + ii * 8;
        GLD16(&kn[(size_t)(rb + sr) * 64 + sg * 8], &Kb[0][rb * 64]);
    }

    // persistent q A-frags: row s0+mB+lm, k = ks*32+kq*8
    bf8 aq[2];
    #pragma unroll
    for (int ks = 0; ks < 2; ++ks)
        aq[ks] = *(const bf8*)&qn[(size_t)(s0 + mB + lm) * 64 + ks * 32 + kq * 8];

    f4 accO[4] = {};
    float m_i[4], l_i[4];
    #pragma unroll
    for (int rg = 0; rg < 4; ++rg) { m_i[rg] = -3.0e38f; l_i[rg] = 0.f; }

    int c = 0;
    for (int tt = 0; tt < 8; ++tt, c ^= 1) {
        const int t0 = tt * 128;
        const bool causal = (tt <= sTT);
        u16* __restrict__ Kc = &Kb[c][0];

        __syncthreads();  // K(tt) staged+visible (full drain); prev LDS reads done

        // V(tt) for this tile (single buffer; prev PV reads completed at barrier)
        if (causal) {
            #pragma unroll
            for (int ii = 0; ii < 4; ++ii) {
                const int rb = w * 16 + ii * 4;
                const int r = rb + vr;
                GLD16(&vn[(size_t)r * 1024 + t0 + ((vg ^ (r & 7)) * 8)], &Vs[rb * 128]);
            }
        }
        // prefetch K(tt+1) into the other buffer
        if (tt < 7) {
            u16* __restrict__ Kn2 = &Kb[c ^ 1][0];
            #pragma unroll
            for (int ii = 0; ii < 4; ++ii) {
                const int rb = w * 32 + ii * 8;
                GLD16(&kn[(size_t)(t0 + 128 + rb + sr) * 64 + sg * 8], &Kn2[rb * 64]);
            }
        }

        // S = q @ k^T for this 64x128 tile
        f4 accS[8] = {};
        __builtin_amdgcn_s_setprio(1);
        #pragma unroll
        for (int ks = 0; ks < 2; ++ks) {
            bf8 b[8];
            #pragma unroll
            for (int ni = 0; ni < 8; ++ni)
                b[ni] = *(bf8*)&Kc[(ni * 16 + lm) * 64 + (((ks * 4 + kq) ^ (lm & 7)) * 8)];
            #pragma unroll
            for (int ni = 0; ni < 8; ++ni)
                accS[ni] = MFMA16(aq[ks], b[ni], accS[ni]);
        }
        __builtin_amdgcn_s_setprio(0);

        // raw heatmap write (unmasked, full matrix); non-temporal stream
        #pragma unroll
        for (int rg = 0; rg < 4; ++rg) {
            float* rowp = &hp[(size_t)(s0 + mB + kq * 4 + rg) * 1024 + t0 + lm];
            #pragma unroll
            for (int ni = 0; ni < 8; ++ni)
                __builtin_nontemporal_store(accS[ni][rg], &rowp[ni * 16]);
        }

        if (causal) {
            // rendezvous: V visible (vmcnt drain) + all waves' S-reads of Kc
            // done (lgkm drain + barrier) before P overlays Kc rows [0,64).
            asm volatile("s_waitcnt vmcnt(0) lgkmcnt(0)" ::: "memory");
            __builtin_amdgcn_s_barrier();
            __builtin_amdgcn_sched_barrier(0);

            const bool diag = (tt == sTT);
            // softmax in registers: p overwrites accS (heat already written)
            #pragma unroll
            for (int rg = 0; rg < 4; ++rg) {
                const int srow = s0 + mB + kq * 4 + rg;
                float tm = -3.0e38f;
                #pragma unroll
                for (int ni = 0; ni < 8; ++ni) {
                    float sv = accS[ni][rg];
                    if (diag && (t0 + ni * 16 + lm > srow)) sv = -3.0e38f;
                    tm = fmaxf(tm, sv);
                }
                tm = fmaxf(tm, __shfl_xor(tm, 1));
                tm = fmaxf(tm, __shfl_xor(tm, 2));
                tm = fmaxf(tm, __shfl_xor(tm, 4));
                tm = fmaxf(tm, __shfl_xor(tm, 8));
                const float mn = fmaxf(m_i[rg], tm);
                const float alpha = __expf(m_i[rg] - mn);
                float rs = 0.f;
                #pragma unroll
                for (int ni = 0; ni < 8; ++ni) {
                    float sv = accS[ni][rg];
                    const bool ok = !diag || (t0 + ni * 16 + lm <= srow);
                    float pv = ok ? __expf(sv - mn) : 0.f;
                    rs += pv;
                    accS[ni][rg] = pv;
                }
                rs += __shfl_xor(rs, 1);
                rs += __shfl_xor(rs, 2);
                rs += __shfl_xor(rs, 4);
                rs += __shfl_xor(rs, 8);
                l_i[rg] = l_i[rg] * alpha + rs;
                m_i[rg] = mn;
                #pragma unroll
                for (int vni = 0; vni < 4; ++vni) accO[vni][rg] *= alpha;
            }

            // PV in two half-passes over t: P half (64 rows x 64 cols = 8KB)
            // overlays Kc rows [0,64). Wave-local rows mB..mB+15; DS order by
            // explicit lgkmcnt(0)+sched_barrier.
            #pragma unroll
            for (int half = 0; half < 2; ++half) {
                #pragma unroll
                for (int rg = 0; rg < 4; ++rg) {
                    const int prow = mB + kq * 4 + rg;
                    #pragma unroll
                    for (int nl = 0; nl < 4; ++nl) {
                        const float pv = accS[half * 4 + nl][rg];
                        Kc[prow * 64 + (((nl * 2 + (lm >> 3)) ^ (prow & 7)) * 8) + (lm & 7)] = f2bf(pv);
                    }
                }
                asm volatile("s_waitcnt lgkmcnt(0)" ::: "memory");
                __builtin_amdgcn_sched_barrier(0);

                __builtin_amdgcn_s_setprio(1);
                #pragma unroll
                for (int kl = 0; kl < 2; ++kl) {
                    const int ks = half * 2 + kl;
                    bf8 a, b[4];
                    a = *(bf8*)&Kc[(mB + lm) * 64 + (((kl * 4 + kq) ^ (lm & 7)) * 8)];
                    #pragma unroll
                    for (int vni = 0; vni < 4; ++vni)
                        b[vni] = *(bf8*)&Vs[(vni * 16 + lm) * 128 + (((ks * 4 + kq) ^ (lm & 7)) * 8)];
                    #pragma unroll
                    for (int vni = 0; vni < 4; ++vni)
                        accO[vni] = MFMA16(a, b[vni], accO[vni]);
                }
                __builtin_amdgcn_s_setprio(0);

                if (half == 0) {
                    // half-0 a-frag reads must retire before half-1 overwrites
                    asm volatile("s_waitcnt lgkmcnt(0)" ::: "memory");
                    __builtin_amdgcn_sched_barrier(0);
                }
            }
        }
    }

    // finalize: O /= l, write wv bf16 [n][s][64]
    u16* __restrict__ wn = wvb + (size_t)n * 65536;
    #pragma unroll
    for (int rg = 0; rg < 4; ++rg) {
        const float li = 1.0f / l_i[rg];
        const int s = s0 + mB + kq * 4 + rg;
        #pragma unroll
        for (int vni = 0; vni < 4; ++vni)
            wn[(size_t)s * 64 + vni * 16 + lm] = f2bf(accO[vni][rg] * li);
    }
}

// ---------------- K5: out = concat_heads(wv) @ Wo + bo ----------------
// grid (4 colTiles, 64 rowTiles), block 256; global_load_lds staging
__global__ __launch_bounds__(256) void k_out(
    const u16* __restrict__ wvb, const u16* __restrict__ WoT, const float* __restrict__ bo,
    float* __restrict__ outp)
{
    const int colTile = blockIdx.x * 128;
    const int rowTile = blockIdx.y * 128;
    const int b = rowTile >> 10, s0 = rowTile & 1023;

    __shared__ __align__(16) u16 As[128 * 64];
    __shared__ __align__(16) u16 Bs[128 * 64];

    const int tid = threadIdx.x;
    const int lane = tid & 63, w = tid >> 6;
    const int lm = lane & 15, kq = lane >> 4;
    const int mB = (w >> 1) * 64, nB = (w & 1) * 64;

    const int sr = lane >> 3;
    const int sg = (lane & 7) ^ sr;

    f4 acc[4][4] = {};

    for (int k0 = 0; k0 < 512; k0 += 64) {
        const int h = k0 >> 6;
        const u16* __restrict__ abase = wvb + (size_t)((h * 8 + b) * 1024 + s0) * 64;
        __syncthreads();
        #pragma unroll
        for (int i = 0; i < 4; ++i) {
            const int rb = w * 32 + i * 8;
            GLD16(&abase[(size_t)(rb + sr) * 64 + sg * 8], &As[rb * 64]);
            GLD16(&WoT[(size_t)(colTile + rb + sr) * 512 + k0 + sg * 8], &Bs[rb * 64]);
        }
        __syncthreads();
        #pragma unroll
        for (int ks = 0; ks < 2; ++ks) {
            bf8 a[4], b2[4];
            #pragma unroll
            for (int mi = 0; mi < 4; ++mi)
                a[mi] = *(bf8*)&As[(mB + mi * 16 + lm) * 64 + (((ks * 4 + kq) ^ (lm & 7)) * 8)];
            #pragma unroll
            for (int ni = 0; ni < 4; ++ni)
                b2[ni] = *(bf8*)&Bs[(nB + ni * 16 + lm) * 64 + (((ks * 4 + kq) ^ (lm & 7)) * 8)];
            #pragma unroll
            for (int mi = 0; mi < 4; ++mi)
                #pragma unroll
                for (int ni = 0; ni < 4; ++ni)
                    acc[mi][ni] = MFMA16(a[mi], b2[ni], acc[mi][ni]);
        }
    }

    #pragma unroll
    for (int mi = 0; mi < 4; ++mi) {
        const int r0 = rowTile + mB + mi * 16 + kq * 4;
        #pragma unroll
        for (int ni = 0; ni < 4; ++ni) {
            const int c = colTile + nB + ni * 16 + lm;
            const float bv_ = bo[c];
            #pragma unroll
            for (int rg = 0; rg < 4; ++rg)
                __builtin_nontemporal_store(acc[mi][ni][rg] + bv_,
                                            &outp[(size_t)(r0 + rg) * 512 + c]);
        }
    }
}

extern "C" void kernel_launch(void* const* d_in, const int* in_sizes, int n_in,
                              void* d_out, int out_size, void* d_ws, size_t ws_size,
                              hipStream_t stream)
{
    (void)in_sizes; (void)n_in; (void)out_size; (void)ws_size;

    const float* x  = (const float*)d_in[0];
    const float* Wq = (const float*)d_in[1];
    const float* bq = (const float*)d_in[2];
    const float* Wk = (const float*)d_in[3];
    const float* bk = (const float*)d_in[4];
    const float* Wv = (const float*)d_in[5];
    const float* bv = (const float*)d_in[6];
    const float* Wo = (const float*)d_in[7];
    const float* bo = (const float*)d_in[8];

    float* outp = (float*)d_out;             // [8,1024,512] fp32
    float* heat = outp + 4194304;            // [64,1024,1024] fp32

    u16* ws16 = (u16*)d_ws;
    u16* xb  = ws16;                          // [8192,512] bf16
    u16* WqT = xb  + 4194304;                 // [512,512] bf16 transposed
    u16* WkT = WqT + 262144;
    u16* WvT = WkT + 262144;
    u16* WoT = WvT + 262144;
    u16* qb  = WoT + 262144;                  // [64,1024,64] bf16
    u16* kb  = qb  + 4194304;                 // [64,1024,64] bf16
    u16* vT  = kb  + 4194304;                 // [64,64,1024] bf16 (v transposed)
    u16* wvb = vT  + 4194304;                 // [64,1024,64] bf16

    k_cvt_x <<<1024, 256, 0, stream>>>((const float4*)x, (ushort4*)xb);
    k_cvt_wT<<<dim3(8, 8, 4), 256, 0, stream>>>(Wq, Wk, Wv, Wo, WqT, WkT, WvT, WoT);
    k_qkv   <<<dim3(4, 64, 3), 256, 0, stream>>>(xb, WqT, WkT, WvT, bq, bk, bv, qb, kb, vT);
    k_attn  <<<dim3(1024), 256, 0, stream>>>(qb, kb, vT, heat, wvb);
    k_out   <<<dim3(4, 64), 256, 0, stream>>>(wvb, WoT, bo, outp);
}